// Round 2
// baseline (110.137 us; speedup 1.0000x reference)
//
#include <hip/hip_runtime.h>
#include <math.h>

// Attention fwd: Q[N,64] K[N,64] V[N,64] fp32 -> O[N,64] fp32
// R2: bf16 MFMA flash attention (32x32x16), swapped-QK layout, 8-way key split.
//
//  - wave = 32 queries (q = lane&31). QK^T = mfma(K, Q) -> D[key, q]:
//    softmax row-reduce is in-lane (16 regs) + one shfl_xor(32).
//  - QK^T k-map is chosen contiguous (sigma(h,j)=h*8+j) for BOTH operands ->
//    layout-agnostic, K frag = one ds_read_b128 from row-major LDS.
//  - PV: pa[kb] = D_{kb>>1} regs [(kb&1)*8 .. +7]  (32x32x16 = two fused
//    32x32x8 halves; standard CDNA mapping). V staged transposed+key-permuted
//    so each V frag is one ds_read_b128.
//  - LDS XOR-swizzle byte ^= (row&7)<<4 on both tiles (G4).
//  - key axis split 8 ways -> 2048 waves (8/CU); partials in d_ws; combine.

typedef __bf16 bf16;
typedef __attribute__((ext_vector_type(4)))  __bf16 bf16x4;
typedef __attribute__((ext_vector_type(8)))  __bf16 bf16x8;
typedef __attribute__((ext_vector_type(16))) float  f32x16;

#define DKc 64
#define DVc 64
#define TK  64    // keys per LDS tile
#define QW  32    // queries per wave
#define NW  4     // waves per block
#define QB  (QW * NW)   // 128 queries per block

__device__ __forceinline__ f32x16 mfma_bf16(bf16x8 a, bf16x8 b, f32x16 c) {
    return __builtin_amdgcn_mfma_f32_32x32x16_bf16(a, b, c, 0, 0, 0);
}

__global__ __launch_bounds__(256, 2)
void attn_fwd_mfma(const float* __restrict__ Q, const float* __restrict__ K,
                   const float* __restrict__ V,
                   float* __restrict__ Opart, float* __restrict__ Mpart,
                   float* __restrict__ Lpart, float* __restrict__ Out,
                   int N, int splits, int chunk) {
    // K tile: [key][dk] bf16 row-major (row = 128 B), XOR-swizzled
    // V tile: [dv][key'] bf16 transposed + key-permuted,  XOR-swizzled
    __shared__ __align__(16) short sK[TK * DKc];
    __shared__ __align__(16) short sV[DVc * TK];

    const int tid  = threadIdx.x;
    const int wid  = tid >> 6;
    const int lane = tid & 63;
    const int l31  = lane & 31;
    const int h    = lane >> 5;

    const int qbase = blockIdx.x * QB + wid * QW;
    const int q     = qbase + l31;
    const int sp    = blockIdx.y;

    // ---- Q fragments (B operand), element (h,j) := Q[q][f*16 + h*8 + j] * 1/8
    bf16x8 qf[4];
#pragma unroll
    for (int f = 0; f < 4; ++f) {
        const float* qp = Q + (size_t)q * DKc + f * 16 + h * 8;
        float4 a = *(const float4*)qp;
        float4 b = *(const float4*)(qp + 4);
        qf[f][0] = (bf16)(a.x * 0.125f); qf[f][1] = (bf16)(a.y * 0.125f);
        qf[f][2] = (bf16)(a.z * 0.125f); qf[f][3] = (bf16)(a.w * 0.125f);
        qf[f][4] = (bf16)(b.x * 0.125f); qf[f][5] = (bf16)(b.y * 0.125f);
        qf[f][6] = (bf16)(b.z * 0.125f); qf[f][7] = (bf16)(b.w * 0.125f);
    }

    f32x16 O0 = {0}, O1 = {0};     // O[q=crow(r,h)][dv = {0,32}+l31]
    float m = -1e30f, lsum = 0.f;

    const int k0 = sp * chunk;
    int k1 = k0 + chunk; if (k1 > N) k1 = N;

    for (int t0 = k0; t0 < k1; t0 += TK) {
        __syncthreads();
        // ---- stage K tile: 64x64 fp32 -> bf16, row-major + swizzle
#pragma unroll
        for (int it = 0; it < 4; ++it) {
            int idx = it * 256 + tid;          // 1024 float4 total
            int key = idx >> 4;
            int dk4 = (idx & 15) * 4;
            float4 kv = *(const float4*)(K + (size_t)(t0 + key) * DKc + dk4);
            bf16x4 w; w[0]=(bf16)kv.x; w[1]=(bf16)kv.y; w[2]=(bf16)kv.z; w[3]=(bf16)kv.w;
            int byte = ((key * DKc + dk4) * 2) ^ ((key & 7) << 4);
            *(bf16x4*)((char*)sK + byte) = w;
        }
        // ---- stage V tile: transpose to [dv][key'], key' = perm(key), swizzle
        {
            int dv = tid & 63, kg = tid >> 6;  // kg: 16-key group
            union { bf16 s[16]; bf16x8 v8[2]; } u;
#pragma unroll
            for (int r = 0; r < 16; ++r) {
                float vv = V[(size_t)(t0 + kg * 16 + r) * DVc + dv];
                int rp = ((r >> 2) & 1) * 8 + (r & 3) + ((r >> 3) << 2);
                u.s[rp] = (bf16)vv;
            }
            int b0 = (dv * TK + kg * 16) * 2;          // 32B block, 2 x 16B
            int sw = (dv & 7) << 4;
            *(bf16x8*)((char*)sV + (b0 ^ sw))        = u.v8[0];
            *(bf16x8*)((char*)sV + ((b0 + 16) ^ sw)) = u.v8[1];
        }
        __syncthreads();

        // ---- QK^T: D[key, q], two 32-key subtiles
        f32x16 d0 = {0}, d1 = {0};
#pragma unroll
        for (int f = 0; f < 4; ++f) {
            int keyA = l31, keyB = 32 + l31;
            int ba = ((keyA * DKc * 2) + f * 32 + h * 16) ^ ((keyA & 7) << 4);
            int bb = ((keyB * DKc * 2) + f * 32 + h * 16) ^ ((keyB & 7) << 4);
            bf16x8 kf0 = *(const bf16x8*)((char*)sK + ba);
            bf16x8 kf1 = *(const bf16x8*)((char*)sK + bb);
            d0 = mfma_bf16(kf0, qf[f], d0);
            d1 = mfma_bf16(kf1, qf[f], d1);
        }

        // ---- online softmax (q = l31; keys spread over regs and lane halves)
        float tm = -1e30f;
#pragma unroll
        for (int r = 0; r < 16; ++r) tm = fmaxf(tm, fmaxf(d0[r], d1[r]));
        tm = fmaxf(tm, __shfl_xor(tm, 32));
        float mn = fmaxf(m, tm);
        float fscale = __expf(m - mn);
        m = mn;

        float psum = 0.f;
#pragma unroll
        for (int r = 0; r < 16; ++r) {
            d0[r] = __expf(d0[r] - mn); psum += d0[r];
            d1[r] = __expf(d1[r] - mn); psum += d1[r];
        }
        psum += __shfl_xor(psum, 32);
        lsum = lsum * fscale + psum;

        // ---- pack P -> A frags: pa[kb] = D_{kb>>1}[(kb&1)*8 + j]
        bf16x8 pa[4];
#pragma unroll
        for (int j = 0; j < 8; ++j) {
            pa[0][j] = (bf16)d0[j];
            pa[1][j] = (bf16)d0[8 + j];
            pa[2][j] = (bf16)d1[j];
            pa[3][j] = (bf16)d1[8 + j];
        }

        // ---- rescale O rows by fscale (row q lives at crow(r,h) -> shuffle)
#pragma unroll
        for (int r = 0; r < 16; ++r) {
            int qr = (r & 3) + 8 * (r >> 2) + 4 * h;
            float fr = __shfl(fscale, (lane & 32) | qr);
            O0[r] *= fr; O1[r] *= fr;
        }

        // ---- PV: O[q, dv] += P V  (4 k-slots of 16 keys)
#pragma unroll
        for (int kb = 0; kb < 4; ++kb) {
            int dvA = l31, dvB = 32 + l31;
            int ba = ((dvA * TK * 2) + kb * 32 + h * 16) ^ ((dvA & 7) << 4);
            int bb = ((dvB * TK * 2) + kb * 32 + h * 16) ^ ((dvB & 7) << 4);
            bf16x8 vf0 = *(const bf16x8*)((char*)sV + ba);
            bf16x8 vf1 = *(const bf16x8*)((char*)sV + bb);
            O0 = mfma_bf16(pa[kb], vf0, O0);
            O1 = mfma_bf16(pa[kb], vf1, O1);
        }
    }

    // ---- epilogue
    if (splits == 1) {
        float inv = 1.f / lsum;
#pragma unroll
        for (int r = 0; r < 16; ++r) {
            int qr = (r & 3) + 8 * (r >> 2) + 4 * h;
            float fr = __shfl(inv, (lane & 32) | qr);
            int qq = qbase + qr;
            Out[(size_t)qq * DVc + l31]      = O0[r] * fr;
            Out[(size_t)qq * DVc + 32 + l31] = O1[r] * fr;
        }
    } else {
#pragma unroll
        for (int r = 0; r < 16; ++r) {
            int qr = (r & 3) + 8 * (r >> 2) + 4 * h;
            int qq = qbase + qr;
            size_t off = ((size_t)sp * N + qq) * DVc;
            Opart[off + l31]      = O0[r];
            Opart[off + 32 + l31] = O1[r];
        }
        if (lane < 32) {
            Mpart[(size_t)sp * N + q] = m;
            Lpart[(size_t)sp * N + q] = lsum;
        }
    }
}

__global__ __launch_bounds__(256)
void attn_combine(const float* __restrict__ Opart, const float* __restrict__ Mpart,
                  const float* __restrict__ Lpart, float* __restrict__ Out,
                  int N, int splits) {
    const int t  = blockIdx.x * blockDim.x + threadIdx.x;  // [0, N*16)
    const int q  = t >> 4;
    const int d4 = t & 15;

    float M = -1e30f;
    for (int s = 0; s < splits; ++s) M = fmaxf(M, Mpart[(size_t)s * N + q]);

    float4 acc = make_float4(0.f, 0.f, 0.f, 0.f);
    float  L = 0.f;
    for (int s = 0; s < splits; ++s) {
        float w = __expf(Mpart[(size_t)s * N + q] - M);
        L += w * Lpart[(size_t)s * N + q];
        float4 ov = *(const float4*)(Opart + ((size_t)s * N + q) * DVc + d4 * 4);
        acc.x += w * ov.x; acc.y += w * ov.y; acc.z += w * ov.z; acc.w += w * ov.w;
    }
    float inv = 1.f / L;
    *(float4*)(Out + (size_t)q * DVc + d4 * 4) =
        make_float4(acc.x * inv, acc.y * inv, acc.z * inv, acc.w * inv);
}

extern "C" void kernel_launch(void* const* d_in, const int* in_sizes, int n_in,
                              void* d_out, int out_size, void* d_ws, size_t ws_size,
                              hipStream_t stream) {
    const float* Q = (const float*)d_in[0];
    const float* K = (const float*)d_in[1];
    const float* V = (const float*)d_in[2];
    float* Out = (float*)d_out;

    const int N = in_sizes[0] / DKc;   // 8192

    int splits = 8;
    while (splits > 1 &&
           (size_t)splits * (size_t)N * (DVc + 2) * sizeof(float) > ws_size)
        splits >>= 1;
    int chunk = (N + splits - 1) / splits;
    chunk = ((chunk + TK - 1) / TK) * TK;

    float* Opart = (float*)d_ws;
    float* Mpart = Opart + (size_t)splits * N * DVc;
    float* Lpart = Mpart + (size_t)splits * N;

    dim3 grid(N / QB, splits);
    attn_fwd_mfma<<<grid, 256, 0, stream>>>(Q, K, V, Opart, Mpart, Lpart, Out,
                                            N, splits, chunk);
    if (splits > 1) {
        int total = N * 16;
        attn_combine<<<total / 256, 256, 0, stream>>>(Opart, Mpart, Lpart, Out,
                                                      N, splits);
    }
}

// Round 3
// 100.564 us; speedup vs baseline: 1.0952x; 1.0952x over previous
//
#include <hip/hip_runtime.h>
#include <math.h>

// Attention fwd: Q[N,64] K[N,64] V[N,64] fp32 -> O[N,64] fp32
// R3: bf16 MFMA flash attention, 32x32x16, swapped-QK layout.
//  - prepass: Qb = bf16(Q * 0.125*log2e), Kb = bf16(K), Vt = bf16 V^T with
//    PV slot-permute baked in. All in d_ws.
//  - main: stage K/V tiles via global_load_lds(16B), swizzle via pre-swizzled
//    SOURCE address (linear LDS dest), XOR swizzle (row&7)<<4 on reads.
//  - softmax in exp2 domain, defer-max THR=10 (rescale O only when the
//    running max grows >10; P bounded by 2^10).
//  - 16-way key split (4 waves/SIMD), partials in d_ws, combine kernel.

typedef __bf16 bf16;
typedef __attribute__((ext_vector_type(4)))  __bf16 bf16x4;
typedef __attribute__((ext_vector_type(8)))  __bf16 bf16x8;
typedef __attribute__((ext_vector_type(16))) float  f32x16;

#define DKc 64
#define DVc 64
#define TK  64
#define QW  32
#define NW  4
#define QB  (QW * NW)   // 128 queries per block
#define SCALE_LOG2E 0.1803368801111204f   // 0.125 * log2(e)

__device__ __forceinline__ f32x16 mfma_bf16(bf16x8 a, bf16x8 b, f32x16 c) {
    return __builtin_amdgcn_mfma_f32_32x32x16_bf16(a, b, c, 0, 0, 0);
}
__device__ __forceinline__ int rp4(int r) {   // PV k-slot permute (involution)
    return ((r >> 2) & 1) * 8 + (r & 3) + ((r >> 3) << 2);
}

// ---------------- prepass: fp32 -> bf16 (+ scale, + V transpose/permute) ----
__global__ __launch_bounds__(256)
void prepass(const float* __restrict__ Q, const float* __restrict__ K,
             const float* __restrict__ V,
             bf16* __restrict__ Qb, bf16* __restrict__ Kb, bf16* __restrict__ Vt,
             int N) {
    const int b = blockIdx.x, tid = threadIdx.x;
    const int nqb = (N * DKc) / (256 * 4);          // float4 blocks per matrix
    if (b < 2 * nqb) {
        bool isQ = b < nqb;
        int idx = (isQ ? b : b - nqb) * 256 + tid;
        float4 v = (isQ ? (const float4*)Q : (const float4*)K)[idx];
        float sc = isQ ? SCALE_LOG2E : 1.0f;
        bf16x4 w;
        w[0] = (bf16)(v.x * sc); w[1] = (bf16)(v.y * sc);
        w[2] = (bf16)(v.z * sc); w[3] = (bf16)(v.w * sc);
        ((bf16x4*)(isQ ? Qb : Kb))[idx] = w;
    } else {
        // V transpose tile: 64 keys x 64 dv -> Vt[dv][T*64 + permuted key]
        const int T = b - 2 * nqb;
        __shared__ float sT[64][65];
#pragma unroll
        for (int p = 0; p < 4; ++p) {
            int fi = p * 256 + tid;                 // float4 index in tile
            int e0 = fi * 4;
            int key = e0 >> 6, dv = e0 & 63;
            float4 v = ((const float4*)(V + (size_t)T * 64 * DVc))[fi];
            sT[dv + 0][key] = v.x; sT[dv + 1][key] = v.y;
            sT[dv + 2][key] = v.z; sT[dv + 3][key] = v.w;
        }
        __syncthreads();
#pragma unroll
        for (int w = 0; w < 2; ++w) {
            int vidx = w * 256 + tid;
            int dv = vidx >> 3, j0 = (vidx & 7) * 8;
            bf16x8 o;
#pragma unroll
            for (int i = 0; i < 8; ++i) {
                int j = j0 + i;
                int ks = (j & 48) | rp4(j & 15);
                o[i] = (bf16)sT[dv][ks];
            }
            *(bf16x8*)(Vt + (size_t)dv * N + T * 64 + j0) = o;
        }
    }
}

// ---------------- main flash kernel ----------------------------------------
__global__ __launch_bounds__(256, 4)
void attn_fwd_mfma(const bf16* __restrict__ Qb, const bf16* __restrict__ Kb,
                   const bf16* __restrict__ Vt,
                   float* __restrict__ Opart, float* __restrict__ Mpart,
                   float* __restrict__ Lpart, float* __restrict__ Out,
                   int N, int splits, int chunk) {
    __shared__ __align__(16) short sK[TK * DKc];   // [key][dk] bf16, swizzled
    __shared__ __align__(16) short sV[DVc * TK];   // [dv][key'] bf16, swizzled

    const int tid  = threadIdx.x;
    const int wid  = tid >> 6;
    const int lane = tid & 63;
    const int l31  = lane & 31;
    const int h    = lane >> 5;

    const int qbase = blockIdx.x * QB + wid * QW;
    const int q     = qbase + l31;
    const int sp    = blockIdx.y;

    // Q fragments: qf[f][j] = Qb[q][f*16 + h*8 + j]  (one 16B load each)
    bf16x8 qf[4];
#pragma unroll
    for (int f = 0; f < 4; ++f)
        qf[f] = *(const bf16x8*)(Qb + (size_t)q * DKc + f * 16 + h * 8);

    f32x16 O0 = {0}, O1 = {0};
    float m = -1e30f, lsum = 0.f;

    const int k0 = sp * chunk;
    int k1 = k0 + chunk; if (k1 > N) k1 = N;

    const char* KbB = (const char*)Kb;
    const char* VtB = (const char*)Vt;
    char* sKc = (char*)sK;
    char* sVc = (char*)sV;
    const size_t vrow = (size_t)N * 2;             // Vt row stride in bytes

    for (int t0 = k0; t0 < k1; t0 += TK) {
        __syncthreads();
        // ---- stage via global_load_lds: linear dest, pre-swizzled source
#pragma unroll
        for (int p = 0; p < 2; ++p) {
            int o   = p * 4096 + wid * 1024 + lane * 16;
            int key = o >> 7;
            int so  = o ^ ((key & 7) << 4);
            __builtin_amdgcn_global_load_lds(
                (const __attribute__((address_space(1))) void*)(KbB + (size_t)t0 * 128 + so),
                (__attribute__((address_space(3))) void*)(sKc + p * 4096 + wid * 1024),
                16, 0, 0);
        }
#pragma unroll
        for (int p = 0; p < 2; ++p) {
            int o  = p * 4096 + wid * 1024 + lane * 16;
            int dv = o >> 7;
            int kb = o & 127;
            int so = kb ^ ((dv & 7) << 4);
            __builtin_amdgcn_global_load_lds(
                (const __attribute__((address_space(1))) void*)(VtB + (size_t)dv * vrow + (size_t)t0 * 2 + so),
                (__attribute__((address_space(3))) void*)(sVc + p * 4096 + wid * 1024),
                16, 0, 0);
        }
        __syncthreads();

        // ---- QK^T: D[key, q]
        f32x16 d0 = {0}, d1 = {0};
#pragma unroll
        for (int f = 0; f < 4; ++f) {
            int keyA = l31, keyB = 32 + l31;
            int ba = ((keyA * 128) + f * 32 + h * 16) ^ ((keyA & 7) << 4);
            int bb = ((keyB * 128) + f * 32 + h * 16) ^ ((keyB & 7) << 4);
            bf16x8 kf0 = *(const bf16x8*)(sKc + ba);
            bf16x8 kf1 = *(const bf16x8*)(sKc + bb);
            d0 = mfma_bf16(kf0, qf[f], d0);
            d1 = mfma_bf16(kf1, qf[f], d1);
        }

        // ---- online softmax, exp2 domain, defer-max (THR=10)
        float tm = -1e30f;
#pragma unroll
        for (int r = 0; r < 16; ++r) tm = fmaxf(tm, fmaxf(d0[r], d1[r]));
        tm = fmaxf(tm, __shfl_xor(tm, 32));

        float fs = 1.f;
        if (__any(tm > m + 10.f)) {
            float mn = fmaxf(m, tm);
            fs = __builtin_amdgcn_exp2f(m - mn);   // first tile: -> 0
            m = mn;
#pragma unroll
            for (int r = 0; r < 16; ++r) {
                int qr = (r & 3) + 8 * (r >> 2) + 4 * h;
                float fr = __shfl(fs, (lane & 32) | qr);
                O0[r] *= fr; O1[r] *= fr;
            }
        }

        float psum = 0.f;
#pragma unroll
        for (int r = 0; r < 16; ++r) {
            d0[r] = __builtin_amdgcn_exp2f(d0[r] - m); psum += d0[r];
            d1[r] = __builtin_amdgcn_exp2f(d1[r] - m); psum += d1[r];
        }
        psum += __shfl_xor(psum, 32);
        lsum = lsum * fs + psum;

        // ---- pack P -> A frags
        bf16x8 pa[4];
#pragma unroll
        for (int j = 0; j < 8; ++j) {
            pa[0][j] = (bf16)d0[j];
            pa[1][j] = (bf16)d0[8 + j];
            pa[2][j] = (bf16)d1[j];
            pa[3][j] = (bf16)d1[8 + j];
        }

        // ---- PV
#pragma unroll
        for (int kb = 0; kb < 4; ++kb) {
            int dvA = l31, dvB = 32 + l31;
            int ba = ((dvA * 128) + kb * 32 + h * 16) ^ ((dvA & 7) << 4);
            int bb = ((dvB * 128) + kb * 32 + h * 16) ^ ((dvB & 7) << 4);
            bf16x8 vf0 = *(const bf16x8*)(sVc + ba);
            bf16x8 vf1 = *(const bf16x8*)(sVc + bb);
            O0 = mfma_bf16(pa[kb], vf0, O0);
            O1 = mfma_bf16(pa[kb], vf1, O1);
        }
    }

    // ---- epilogue
    if (splits == 1) {
        float inv = 1.f / lsum;
#pragma unroll
        for (int r = 0; r < 16; ++r) {
            int qr = (r & 3) + 8 * (r >> 2) + 4 * h;
            float fr = __shfl(inv, (lane & 32) | qr);
            int qq = qbase + qr;
            Out[(size_t)qq * DVc + l31]      = O0[r] * fr;
            Out[(size_t)qq * DVc + 32 + l31] = O1[r] * fr;
        }
    } else {
#pragma unroll
        for (int r = 0; r < 16; ++r) {
            int qr = (r & 3) + 8 * (r >> 2) + 4 * h;
            int qq = qbase + qr;
            size_t off = ((size_t)sp * N + qq) * DVc;
            Opart[off + l31]      = O0[r];
            Opart[off + 32 + l31] = O1[r];
        }
        if (lane < 32) {
            Mpart[(size_t)sp * N + q] = m;
            Lpart[(size_t)sp * N + q] = lsum;
        }
    }
}

// ---------------- combine (exp2 domain) ------------------------------------
__global__ __launch_bounds__(256)
void attn_combine(const float* __restrict__ Opart, const float* __restrict__ Mpart,
                  const float* __restrict__ Lpart, float* __restrict__ Out,
                  int N, int splits) {
    const int t  = blockIdx.x * blockDim.x + threadIdx.x;
    const int q  = t >> 4;
    const int d4 = t & 15;

    float M = -1e30f;
    for (int s = 0; s < splits; ++s) M = fmaxf(M, Mpart[(size_t)s * N + q]);

    float4 acc = make_float4(0.f, 0.f, 0.f, 0.f);
    float  L = 0.f;
    for (int s = 0; s < splits; ++s) {
        float w = __builtin_amdgcn_exp2f(Mpart[(size_t)s * N + q] - M);
        L += w * Lpart[(size_t)s * N + q];
        float4 ov = *(const float4*)(Opart + ((size_t)s * N + q) * DVc + d4 * 4);
        acc.x += w * ov.x; acc.y += w * ov.y; acc.z += w * ov.z; acc.w += w * ov.w;
    }
    float inv = 1.f / L;
    *(float4*)(Out + (size_t)q * DVc + d4 * 4) =
        make_float4(acc.x * inv, acc.y * inv, acc.z * inv, acc.w * inv);
}

extern "C" void kernel_launch(void* const* d_in, const int* in_sizes, int n_in,
                              void* d_out, int out_size, void* d_ws, size_t ws_size,
                              hipStream_t stream) {
    const float* Q = (const float*)d_in[0];
    const float* K = (const float*)d_in[1];
    const float* V = (const float*)d_in[2];
    float* Out = (float*)d_out;

    const int N = in_sizes[0] / DKc;   // 8192

    // ws layout: Qb | Kb | Vt (bf16, N*64 each) | Opart | Mpart | Lpart
    const size_t bfbytes = (size_t)N * DKc * sizeof(short);
    bf16* Qb = (bf16*)d_ws;
    bf16* Kb = (bf16*)((char*)d_ws + bfbytes);
    bf16* Vt = (bf16*)((char*)d_ws + 2 * bfbytes);
    char* rest = (char*)d_ws + 3 * bfbytes;
    size_t rest_sz = (ws_size > 3 * bfbytes) ? ws_size - 3 * bfbytes : 0;

    int splits = 16;
    while (splits > 1 &&
           (size_t)splits * (size_t)N * (DVc + 2) * sizeof(float) > rest_sz)
        splits >>= 1;
    int chunk = (N + splits - 1) / splits;
    chunk = ((chunk + TK - 1) / TK) * TK;

    float* Opart = (float*)rest;
    float* Mpart = Opart + (size_t)splits * N * DVc;
    float* Lpart = Mpart + (size_t)splits * N;

    const int nqb = (N * DKc) / (256 * 4);
    prepass<<<2 * nqb + N / TK, 256, 0, stream>>>(Q, K, V, Qb, Kb, Vt, N);

    dim3 grid(N / QB, splits);
    attn_fwd_mfma<<<grid, 256, 0, stream>>>(Qb, Kb, Vt, Opart, Mpart, Lpart, Out,
                                            N, splits, chunk);
    if (splits > 1) {
        int total = N * 16;
        attn_combine<<<total / 256, 256, 0, stream>>>(Opart, Mpart, Lpart, Out,
                                                      N, splits);
    }
}

// Round 5
// 100.231 us; speedup vs baseline: 1.0988x; 1.0033x over previous
//
#include <hip/hip_runtime.h>
#include <math.h>

// Attention fwd: Q[N,64] K[N,64] V[N,64] fp32 -> O[N,64] fp32
// R4 (resubmit): R3 + double-buffered LDS staging with counted vmcnt (T3/T4):
//  - prologue stages tile0; each iter issues tile t+1 into buf^1, then
//    s_waitcnt vmcnt(4) (current tile's 4 loads only - never drain to 0),
//    sched_barrier, raw s_barrier, compute, raw s_barrier.
//  - prepass: Qb = bf16(Q * 0.125*log2e), Kb = bf16(K), Vt = bf16 V^T with
//    PV slot-permute baked in. global_load_lds with pre-swizzled source,
//    XOR swizzle (row&7)<<4 on LDS reads.
//  - softmax in exp2 domain, defer-max THR=10.
//  - 16-way key split, partials in d_ws, combine kernel.

typedef __bf16 bf16;
typedef __attribute__((ext_vector_type(4)))  __bf16 bf16x4;
typedef __attribute__((ext_vector_type(8)))  __bf16 bf16x8;
typedef __attribute__((ext_vector_type(16))) float  f32x16;

#define DKc 64
#define DVc 64
#define TK  64
#define QW  32
#define NW  4
#define QB  (QW * NW)   // 128 queries per block
#define SCALE_LOG2E 0.1803368801111204f   // 0.125 * log2(e)

__device__ __forceinline__ f32x16 mfma_bf16(bf16x8 a, bf16x8 b, f32x16 c) {
    return __builtin_amdgcn_mfma_f32_32x32x16_bf16(a, b, c, 0, 0, 0);
}
__device__ __forceinline__ int rp4(int r) {   // PV k-slot permute (involution)
    return ((r >> 2) & 1) * 8 + (r & 3) + ((r >> 3) << 2);
}

// ---------------- prepass: fp32 -> bf16 (+ scale, + V transpose/permute) ----
__global__ __launch_bounds__(256)
void prepass(const float* __restrict__ Q, const float* __restrict__ K,
             const float* __restrict__ V,
             bf16* __restrict__ Qb, bf16* __restrict__ Kb, bf16* __restrict__ Vt,
             int N) {
    const int b = blockIdx.x, tid = threadIdx.x;
    const int nqb = (N * DKc) / (256 * 4);          // float4 blocks per matrix
    if (b < 2 * nqb) {
        bool isQ = b < nqb;
        int idx = (isQ ? b : b - nqb) * 256 + tid;
        float4 v = (isQ ? (const float4*)Q : (const float4*)K)[idx];
        float sc = isQ ? SCALE_LOG2E : 1.0f;
        bf16x4 w;
        w[0] = (bf16)(v.x * sc); w[1] = (bf16)(v.y * sc);
        w[2] = (bf16)(v.z * sc); w[3] = (bf16)(v.w * sc);
        ((bf16x4*)(isQ ? Qb : Kb))[idx] = w;
    } else {
        // V transpose tile: 64 keys x 64 dv -> Vt[dv][T*64 + permuted key]
        const int T = b - 2 * nqb;
        __shared__ float sT[64][65];
#pragma unroll
        for (int p = 0; p < 4; ++p) {
            int fi = p * 256 + tid;                 // float4 index in tile
            int e0 = fi * 4;
            int key = e0 >> 6, dv = e0 & 63;
            float4 v = ((const float4*)(V + (size_t)T * 64 * DVc))[fi];
            sT[dv + 0][key] = v.x; sT[dv + 1][key] = v.y;
            sT[dv + 2][key] = v.z; sT[dv + 3][key] = v.w;
        }
        __syncthreads();
#pragma unroll
        for (int w = 0; w < 2; ++w) {
            int vidx = w * 256 + tid;
            int dv = vidx >> 3, j0 = (vidx & 7) * 8;
            bf16x8 o;
#pragma unroll
            for (int i = 0; i < 8; ++i) {
                int j = j0 + i;
                int ks = (j & 48) | rp4(j & 15);
                o[i] = (bf16)sT[dv][ks];
            }
            *(bf16x8*)(Vt + (size_t)dv * N + T * 64 + j0) = o;
        }
    }
}

// ---------------- main flash kernel ----------------------------------------
__global__ __launch_bounds__(256, 4)
void attn_fwd_mfma(const bf16* __restrict__ Qb, const bf16* __restrict__ Kb,
                   const bf16* __restrict__ Vt,
                   float* __restrict__ Opart, float* __restrict__ Mpart,
                   float* __restrict__ Lpart, float* __restrict__ Out,
                   int N, int splits, int chunk) {
    // double-buffered tiles, 8 KB each: [key][dk] / [dv][key'], swizzled
    __shared__ __align__(16) short sK[2][TK * DKc];
    __shared__ __align__(16) short sV[2][DVc * TK];

    const int tid  = threadIdx.x;
    const int wid  = tid >> 6;
    const int lane = tid & 63;
    const int l31  = lane & 31;
    const int h    = lane >> 5;

    const int qbase = blockIdx.x * QB + wid * QW;
    const int q     = qbase + l31;
    const int sp    = blockIdx.y;

    // Q fragments: qf[f][j] = Qb[q][f*16 + h*8 + j]  (one 16B load each)
    bf16x8 qf[4];
#pragma unroll
    for (int f = 0; f < 4; ++f)
        qf[f] = *(const bf16x8*)(Qb + (size_t)q * DKc + f * 16 + h * 8);

    f32x16 O0 = {0}, O1 = {0};
    float m = -1e30f, lsum = 0.f;

    const int k0 = sp * chunk;
    int k1 = k0 + chunk; if (k1 > N) k1 = N;
    const int ntiles = (k1 - k0) / TK;

    const char* KbB = (const char*)Kb;
    const char* VtB = (const char*)Vt;
    const size_t vrow = (size_t)N * 2;             // Vt row stride in bytes

    // issue one tile's staging loads (4 global_load_lds / thread)
    auto stage = [&](int buf, int t0) {
        char* sKb = (char*)&sK[buf][0];
        char* sVb = (char*)&sV[buf][0];
#pragma unroll
        for (int p = 0; p < 2; ++p) {
            int o   = p * 4096 + wid * 1024 + lane * 16;
            int key = o >> 7;
            int so  = o ^ ((key & 7) << 4);
            __builtin_amdgcn_global_load_lds(
                (const __attribute__((address_space(1))) void*)(KbB + (size_t)t0 * 128 + so),
                (__attribute__((address_space(3))) void*)(sKb + p * 4096 + wid * 1024),
                16, 0, 0);
        }
#pragma unroll
        for (int p = 0; p < 2; ++p) {
            int o  = p * 4096 + wid * 1024 + lane * 16;
            int dv = o >> 7;
            int kb = o & 127;
            int so = kb ^ ((dv & 7) << 4);
            __builtin_amdgcn_global_load_lds(
                (const __attribute__((address_space(1))) void*)(VtB + (size_t)dv * vrow + (size_t)t0 * 2 + so),
                (__attribute__((address_space(3))) void*)(sVb + p * 4096 + wid * 1024),
                16, 0, 0);
        }
    };

    stage(0, k0);
    int cur = 0;

    for (int it = 0; it < ntiles; ++it) {
        if (it + 1 < ntiles) {
            stage(cur ^ 1, k0 + (it + 1) * TK);
            // wait only the 4 OLDEST vmem ops = current tile's loads
            // (issued one compute-phase ago); next tile's 4 stay in flight.
            asm volatile("s_waitcnt vmcnt(4)" ::: "memory");
        } else {
            asm volatile("s_waitcnt vmcnt(0)" ::: "memory");
        }
        __builtin_amdgcn_sched_barrier(0);
        __builtin_amdgcn_s_barrier();

        const char* sKc = (const char*)&sK[cur][0];
        const char* sVc = (const char*)&sV[cur][0];

        // ---- QK^T: D[key, q]
        f32x16 d0 = {0}, d1 = {0};
#pragma unroll
        for (int f = 0; f < 4; ++f) {
            int keyA = l31, keyB = 32 + l31;
            int ba = ((keyA * 128) + f * 32 + h * 16) ^ ((keyA & 7) << 4);
            int bb = ((keyB * 128) + f * 32 + h * 16) ^ ((keyB & 7) << 4);
            bf16x8 kf0 = *(const bf16x8*)(sKc + ba);
            bf16x8 kf1 = *(const bf16x8*)(sKc + bb);
            d0 = mfma_bf16(kf0, qf[f], d0);
            d1 = mfma_bf16(kf1, qf[f], d1);
        }

        // ---- online softmax, exp2 domain, defer-max (THR=10)
        float tm = -1e30f;
#pragma unroll
        for (int r = 0; r < 16; ++r) tm = fmaxf(tm, fmaxf(d0[r], d1[r]));
        tm = fmaxf(tm, __shfl_xor(tm, 32));

        float fs = 1.f;
        if (__any(tm > m + 10.f)) {
            float mn = fmaxf(m, tm);
            fs = __builtin_amdgcn_exp2f(m - mn);   // first tile: -> 0
            m = mn;
#pragma unroll
            for (int r = 0; r < 16; ++r) {
                int qr = (r & 3) + 8 * (r >> 2) + 4 * h;
                float fr = __shfl(fs, (lane & 32) | qr);
                O0[r] *= fr; O1[r] *= fr;
            }
        }

        float psum = 0.f;
#pragma unroll
        for (int r = 0; r < 16; ++r) {
            d0[r] = __builtin_amdgcn_exp2f(d0[r] - m); psum += d0[r];
            d1[r] = __builtin_amdgcn_exp2f(d1[r] - m); psum += d1[r];
        }
        psum += __shfl_xor(psum, 32);
        lsum = lsum * fs + psum;

        // ---- pack P -> A frags
        bf16x8 pa[4];
#pragma unroll
        for (int j = 0; j < 8; ++j) {
            pa[0][j] = (bf16)d0[j];
            pa[1][j] = (bf16)d0[8 + j];
            pa[2][j] = (bf16)d1[j];
            pa[3][j] = (bf16)d1[8 + j];
        }

        // ---- PV
#pragma unroll
        for (int kb = 0; kb < 4; ++kb) {
            int dvA = l31, dvB = 32 + l31;
            int ba = ((dvA * 128) + kb * 32 + h * 16) ^ ((dvA & 7) << 4);
            int bb = ((dvB * 128) + kb * 32 + h * 16) ^ ((dvB & 7) << 4);
            bf16x8 vf0 = *(const bf16x8*)(sVc + ba);
            bf16x8 vf1 = *(const bf16x8*)(sVc + bb);
            O0 = mfma_bf16(pa[kb], vf0, O0);
            O1 = mfma_bf16(pa[kb], vf1, O1);
        }

        __builtin_amdgcn_s_barrier();   // all waves done reading buf[cur]
        cur ^= 1;
    }

    // ---- epilogue
    if (splits == 1) {
        float inv = 1.f / lsum;
#pragma unroll
        for (int r = 0; r < 16; ++r) {
            int qr = (r & 3) + 8 * (r >> 2) + 4 * h;
            float fr = __shfl(inv, (lane & 32) | qr);
            int qq = qbase + qr;
            Out[(size_t)qq * DVc + l31]      = O0[r] * fr;
            Out[(size_t)qq * DVc + 32 + l31] = O1[r] * fr;
        }
    } else {
#pragma unroll
        for (int r = 0; r < 16; ++r) {
            int qr = (r & 3) + 8 * (r >> 2) + 4 * h;
            int qq = qbase + qr;
            size_t off = ((size_t)sp * N + qq) * DVc;
            Opart[off + l31]      = O0[r];
            Opart[off + 32 + l31] = O1[r];
        }
        if (lane < 32) {
            Mpart[(size_t)sp * N + q] = m;
            Lpart[(size_t)sp * N + q] = lsum;
        }
    }
}

// ---------------- combine (exp2 domain) ------------------------------------
__global__ __launch_bounds__(256)
void attn_combine(const float* __restrict__ Opart, const float* __restrict__ Mpart,
                  const float* __restrict__ Lpart, float* __restrict__ Out,
                  int N, int splits) {
    const int t  = blockIdx.x * blockDim.x + threadIdx.x;
    const int q  = t >> 4;
    const int d4 = t & 15;

    float M = -1e30f;
    for (int s = 0; s < splits; ++s) M = fmaxf(M, Mpart[(size_t)s * N + q]);

    float4 acc = make_float4(0.f, 0.f, 0.f, 0.f);
    float  L = 0.f;
    for (int s = 0; s < splits; ++s) {
        float w = __builtin_amdgcn_exp2f(Mpart[(size_t)s * N + q] - M);
        L += w * Lpart[(size_t)s * N + q];
        float4 ov = *(const float4*)(Opart + ((size_t)s * N + q) * DVc + d4 * 4);
        acc.x += w * ov.x; acc.y += w * ov.y; acc.z += w * ov.z; acc.w += w * ov.w;
    }
    float inv = 1.f / L;
    *(float4*)(Out + (size_t)q * DVc + d4 * 4) =
        make_float4(acc.x * inv, acc.y * inv, acc.z * inv, acc.w * inv);
}

extern "C" void kernel_launch(void* const* d_in, const int* in_sizes, int n_in,
                              void* d_out, int out_size, void* d_ws, size_t ws_size,
                              hipStream_t stream) {
    const float* Q = (const float*)d_in[0];
    const float* K = (const float*)d_in[1];
    const float* V = (const float*)d_in[2];
    float* Out = (float*)d_out;

    const int N = in_sizes[0] / DKc;   // 8192

    // ws layout: Qb | Kb | Vt (bf16, N*64 each) | Opart | Mpart | Lpart
    const size_t bfbytes = (size_t)N * DKc * sizeof(short);
    bf16* Qb = (bf16*)d_ws;
    bf16* Kb = (bf16*)((char*)d_ws + bfbytes);
    bf16* Vt = (bf16*)((char*)d_ws + 2 * bfbytes);
    char* rest = (char*)d_ws + 3 * bfbytes;
    size_t rest_sz = (ws_size > 3 * bfbytes) ? ws_size - 3 * bfbytes : 0;

    int splits = 16;
    while (splits > 1 &&
           (size_t)splits * (size_t)N * (DVc + 2) * sizeof(float) > rest_sz)
        splits >>= 1;
    int chunk = (N + splits - 1) / splits;
    chunk = ((chunk + TK - 1) / TK) * TK;

    float* Opart = (float*)rest;
    float* Mpart = Opart + (size_t)splits * N * DVc;
    float* Lpart = Mpart + (size_t)splits * N;

    const int nqb = (N * DKc) / (256 * 4);
    prepass<<<2 * nqb + N / TK, 256, 0, stream>>>(Q, K, V, Qb, Kb, Vt, N);

    dim3 grid(N / QB, splits);
    attn_fwd_mfma<<<grid, 256, 0, stream>>>(Qb, Kb, Vt, Opart, Mpart, Lpart, Out,
                                            N, splits, chunk);
    if (splits > 1) {
        int total = N * 16;
        attn_combine<<<total / 256, 256, 0, stream>>>(Opart, Mpart, Lpart, Out,
                                                      N, splits);
    }
}